// Round 4
// baseline (623.500 us; speedup 1.0000x reference)
//
#include <hip/hip_runtime.h>
#include <hip/hip_bf16.h>
#include <cstdint>
#include <cstddef>

typedef __attribute__((ext_vector_type(8))) short short8;
typedef __attribute__((ext_vector_type(4))) short short4v;
typedef __attribute__((ext_vector_type(4))) float float4v;

#define S_LEN 2048
#define NHEADS 16
#define DHEAD 128

__device__ __forceinline__ short f2bf(float f) {
    union { float f; unsigned u; } v; v.f = f;
    unsigned r = (v.u + 0x7fffu + ((v.u >> 16) & 1u)) >> 16;
    return (short)(r & 0xffffu);
}
// round-half-up bf16 pack: 2 VALU ops, error <= 1 ulp vs RNE
__device__ __forceinline__ short f2bf_rhu(float f) {
    union { float f; unsigned u; } v; v.f = f;
    return (short)((v.u + 0x8000u) >> 16);
}

typedef __attribute__((address_space(1))) void gvoid;
typedef __attribute__((address_space(3))) void lvoid;

__device__ __forceinline__ void gl_lds16(const void* g, void* l) {
    __builtin_amdgcn_global_load_lds((gvoid*)g, (lvoid*)l, 16, 0, 0);
}

__device__ __forceinline__ float4v mfma16(short8 a, short8 b, float4v c) {
    return __builtin_amdgcn_mfma_f32_16x16x32_bf16(a, b, c, 0, 0, 0);
}

// swizzled LDS tile addressing: tiles are arrays of 16B chunks.
// lds8: 8-chunk rows (128 bf16), swizzle over 8 chunks
__device__ __forceinline__ const char* lds8(const short* base, int row, int ch) {
    return (const char*)base + (((row << 3) + (ch ^ (row & 7))) << 4);
}
// lds16a: 16-chunk rows (128 bf16 cols stored as 16 chunks), swizzle over 16
__device__ __forceinline__ const char* lds16a(const short* base, int row, int ch) {
    return (const char*)base + (((row << 4) + (ch ^ (row & 15))) << 4);
}
// lds4: 4-chunk rows (32 bf16), swizzle uses (row>>1)&3
__device__ __forceinline__ const char* lds4(const short* base, int row, int ch) {
    return (const char*)base + (((row << 2) + (ch ^ ((row >> 1) & 3))) << 4);
}

// ---------------- elementwise fp32 -> bf16 ----------------
__global__ __launch_bounds__(256)
void cvt_bf16(const float* __restrict__ X, short* __restrict__ Y) {
    size_t i = ((size_t)blockIdx.x * 256 + threadIdx.x) * 4;
    float4v v = *(const float4v*)(X + i);
    short4v o;
#pragma unroll
    for (int j = 0; j < 4; ++j) o[j] = f2bf(v[j]);
    *(short4v*)(Y + i) = o;
}

// ---------------- W[K][N] fp32 -> Wt[N][K] bf16, optional pre-scale ----------------
__global__ __launch_bounds__(256)
void tposew(const float* __restrict__ W, short* __restrict__ Wt, int K, int N, float scale) {
    __shared__ float t[32][33];
    int bx = blockIdx.x, by = blockIdx.y;
    int tx = threadIdx.x & 31, ty = threadIdx.x >> 5;
#pragma unroll
    for (int i = 0; i < 32; i += 8)
        t[ty + i][tx] = W[(size_t)(by * 32 + ty + i) * N + bx * 32 + tx];
    __syncthreads();
#pragma unroll
    for (int i = 0; i < 32; i += 8)
        Wt[(size_t)(bx * 32 + ty + i) * K + by * 32 + tx] = f2bf(t[tx][ty + i] * scale);
}

// ---------------- BT-GEMM: C[M][N] = A[M][K] * Bt[N][K]^T (bf16 in, f32 acc) ----
// (round-0 proven single-buffer form; dbuf variant regressed -13us via occupancy)
// MODE 0: store bf16 row-major; MODE 1: store f32 row-major;
// MODE 2: store bf16 scattered as Vt[b][n][s] (n = h*128+dh), i.e. ((b*2048+n)*2048 + s)
template <int MODE>
__global__ __launch_bounds__(256, 2)
void gemm_bt(const short* __restrict__ A, const short* __restrict__ Bt,
             void* __restrict__ Cv, int M, int N, int K) {
    __shared__ short sA[128 * 64];
    __shared__ short sB[128 * 64];
    const int tid = threadIdx.x;
    const int wid = tid >> 6, lane = tid & 63;
    const int quad = lane >> 4, l15 = lane & 15;
    const int n0 = blockIdx.x * 128, m0 = blockIdx.y * 128;
    const int wm = (wid & 1) * 64, wn = (wid >> 1) * 64;
    float4v acc[4][4] = {};
    for (int k0 = 0; k0 < K; k0 += 64) {
        __syncthreads();
#pragma unroll
        for (int i = 0; i < 4; ++i) {
            int c = i * 256 + tid;
            int row = c >> 3, kc = c & 7, g = kc ^ (row & 7);
            int lb = ((i << 8) + (wid << 6)) << 4;
            gl_lds16(A + (size_t)(m0 + row) * K + k0 + g * 8, (char*)(void*)sA + lb);
            gl_lds16(Bt + (size_t)(n0 + row) * K + k0 + g * 8, (char*)(void*)sB + lb);
        }
        __syncthreads();
#pragma unroll
        for (int ks = 0; ks < 2; ++ks) {
            short8 af[4], bf[4];
#pragma unroll
            for (int t = 0; t < 4; ++t) {
                int q = ks * 4 + quad;
                af[t] = *(const short8*)lds8(sA, wm + t * 16 + l15, q);
                bf[t] = *(const short8*)lds8(sB, wn + t * 16 + l15, q);
            }
#pragma unroll
            for (int mt = 0; mt < 4; ++mt)
#pragma unroll
                for (int nt = 0; nt < 4; ++nt)
                    acc[mt][nt] = mfma16(af[mt], bf[nt], acc[mt][nt]);
        }
    }
#pragma unroll
    for (int mt = 0; mt < 4; ++mt)
#pragma unroll
        for (int nt = 0; nt < 4; ++nt) {
            int rbase = m0 + wm + mt * 16 + quad * 4;
            int col = n0 + wn + nt * 16 + l15;
            if (MODE == 0) {
                short* Cb = (short*)Cv;
#pragma unroll
                for (int i = 0; i < 4; ++i)
                    Cb[(size_t)(rbase + i) * N + col] = f2bf(acc[mt][nt][i]);
            } else if (MODE == 1) {
                float* Cf = (float*)Cv;
#pragma unroll
                for (int i = 0; i < 4; ++i)
                    Cf[(size_t)(rbase + i) * N + col] = acc[mt][nt][i];
            } else {
                short4v pk;
#pragma unroll
                for (int i = 0; i < 4; ++i) pk[i] = f2bf(acc[mt][nt][i]);
                int bb = rbase >> 11, s = rbase & 2047;
                short* Cb = (short*)Cv;
                *(short4v*)(Cb + ((size_t)(bb * 2048 + col) * 2048 + s)) = pk;
            }
        }
}

// ---------------- fused differential attention (v7: swapped QK^T, packed P) ----
// Q pre-scaled by (1/sqrt(128))*log2(e) via Wq fold -> scores exit the MFMA in
// log2-domain. Pass 2 folds normalizers into exp args: t1/l1*log2e = exp2(s1+c1).
// SWAPPED QK^T: mfma(K_frag, Q_frag) -> acc[r] = S[key = kb*16+quad*4+r][q = qb*16+l15].
// A/B frags share lane layout (lane(quad,l15) holds Op[l15][quad*8+j]), so the swap
// only transposes the acc. Benefits:
//   - l1/l2/lda accumulate IN-LANE over (kb,r); cross-key reduce = xor16+xor32 only
//   - c1/c2 are 2 scalars (indexed by qb), consumed at lane l15 = own q-row
//   - P-store: 4 consecutive keys per lane -> 4 x ds_write_b64 per tile (was 16 x b16)
// P-tile LDS layout: row = qb*16+l15 (q-row), 64B/row; 16B chunk p = key>>3,
// swizzled p^(row&3); b64 half = (quad&1). PV reads b128 at chunk quad^(l15&3).
// Staging: v6's correct dbuf (barrier -> issue next -> compute). LDS 56KB, 2 blk/CU.
// Q,Kq: bf16 [4096][4096] (col = h*256 + split*128 + dh)
// Vt:   bf16 [B][NH][DH][S];  AO: f32 [4096][2048]
__global__ __launch_bounds__(256, 2)
void attn_kernel(const short* __restrict__ Q, const short* __restrict__ Kq,
                 const short* __restrict__ Vt, const float* __restrict__ lam,
                 float* __restrict__ AO) {
    __shared__ short sK1[2][32 * 128];  // 2 x 8 KB
    __shared__ short sK2[2][32 * 128];  // 2 x 8 KB
    __shared__ short sV[2][128 * 32];   // 2 x 8 KB
    __shared__ short sP[4][32 * 32];    // 8 KB (2 KB/wave)

    const int tid = threadIdx.x;
    const int wid = tid >> 6, lane = tid & 63;
    const int quad = lane >> 4, l15 = lane & 15;

    // XCD swizzle: 4 consecutive bh per XCD (perf heuristic only)
    const int xb = blockIdx.x;
    const int local = xb >> 3;
    const int bh = (xb & 7) * 4 + (local >> 4);
    const int qx = local & 15;
    const int b = bh >> 4, h = bh & 15;
    const int wrow = qx * 128 + wid * 32;

    const float lamh = lam[h];
    const float C0 = 0.5287663729448977f;  // log2(log2(e))

    short8 q1f[2][4], q2f[2][4];
    {
        const short* qb = Q + (size_t)(b * S_LEN + wrow) * 4096 + h * 256;
#pragma unroll
        for (int mt = 0; mt < 2; ++mt)
#pragma unroll
            for (int ks = 0; ks < 4; ++ks) {
                const short* p = qb + (size_t)(mt * 16 + l15) * 4096 + ks * 32 + quad * 8;
                q1f[mt][ks] = *(const short8*)p;
                q2f[mt][ks] = *(const short8*)(p + 128);
            }
    }
    const short* k1g = Kq + (size_t)(b * S_LEN) * 4096 + h * 256;
    const short* k2g = k1g + 128;
    const short* vg = Vt + (size_t)(b * NHEADS + h) * DHEAD * S_LEN;

    int offK[2], offV[2], lbs[2];
#pragma unroll
    for (int i = 0; i < 2; ++i) {
        int c = i * 256 + tid;
        int row = c >> 4, kc = c & 15;
        offK[i] = row * 4096 + ((kc ^ (row & 15)) << 3);
        int dh = c >> 2, vc = c & 3;
        offV[i] = dh * 2048 + ((vc ^ ((dh >> 1) & 3)) << 3);
        lbs[i] = ((i << 8) + (wid << 6)) << 4;  // wave-uniform LDS base
    }

    float l1a[2] = {}, l2a[2] = {};

    const int NT = S_LEN / 32;  // 64 tiles

    // ---- pass 1: l1 = sum exp2(s1), l2 = sum exp2(s2)
#pragma unroll
    for (int i = 0; i < 2; ++i) {
        gl_lds16(k1g + offK[i], (char*)(void*)sK1[0] + lbs[i]);
        gl_lds16(k2g + offK[i], (char*)(void*)sK2[0] + lbs[i]);
    }
    for (int it = 0; it < NT; ++it) {
        __syncthreads();  // drains tile it's loads (flew under tile it-1's compute)
        if (it + 1 < NT) {
            const short* k1b = k1g + (size_t)(it + 1) * 32 * 4096;
            const short* k2b = k2g + (size_t)(it + 1) * 32 * 4096;
            char* dK1 = (char*)(void*)sK1[(it + 1) & 1];
            char* dK2 = (char*)(void*)sK2[(it + 1) & 1];
#pragma unroll
            for (int i = 0; i < 2; ++i) {
                gl_lds16(k1b + offK[i], dK1 + lbs[i]);
                gl_lds16(k2b + offK[i], dK2 + lbs[i]);
            }
        }
        const short* k1 = sK1[it & 1];
        const short* k2 = sK2[it & 1];
#pragma unroll
        for (int kb = 0; kb < 2; ++kb) {
            float4v s1[2] = {}, s2[2] = {};
            int krow = kb * 16 + l15;
            __builtin_amdgcn_s_setprio(1);
#pragma unroll
            for (int ks = 0; ks < 4; ++ks) {
                int q = ks * 4 + quad;
                short8 kf1 = *(const short8*)lds16a(k1, krow, q);
                short8 kf2 = *(const short8*)lds16a(k2, krow, q);
#pragma unroll
                for (int qb = 0; qb < 2; ++qb) {
                    s1[qb] = mfma16(kf1, q1f[qb][ks], s1[qb]);
                    s2[qb] = mfma16(kf2, q2f[qb][ks], s2[qb]);
                }
            }
            __builtin_amdgcn_s_setprio(0);
#pragma unroll
            for (int qb = 0; qb < 2; ++qb)
#pragma unroll
                for (int r = 0; r < 4; ++r) {
                    l1a[qb] += __builtin_amdgcn_exp2f(s1[qb][r]);
                    l2a[qb] += __builtin_amdgcn_exp2f(s2[qb][r]);
                }
        }
    }

    // prologue for pass 2: issue tile 0 (K1,K2,V) into buf 0 (WAR-safe: buf 0 last
    // read at pass-1 it=NT-2, all waves past barrier at top of NT-1)
#pragma unroll
    for (int i = 0; i < 2; ++i) {
        gl_lds16(k1g + offK[i], (char*)(void*)sK1[0] + lbs[i]);
        gl_lds16(k2g + offK[i], (char*)(void*)sK2[0] + lbs[i]);
        gl_lds16(vg + offV[i], (char*)(void*)sV[0] + lbs[i]);
    }

    // cross-key reduce: keys live across quads only (in-lane over kb,r already)
#pragma unroll
    for (int qb = 0; qb < 2; ++qb) {
        l1a[qb] += __shfl_xor(l1a[qb], 16, 64);
        l1a[qb] += __shfl_xor(l1a[qb], 32, 64);
        l2a[qb] += __shfl_xor(l2a[qb], 16, 64);
        l2a[qb] += __shfl_xor(l2a[qb], 32, 64);
    }
    const float llam = __log2f(lamh);
    float c1[2], c2[2];
#pragma unroll
    for (int qb = 0; qb < 2; ++qb) {
        c1[qb] = C0 - __log2f(l1a[qb]);
        c2[qb] = C0 + llam - __log2f(l2a[qb]);
    }

    float lda[2] = {};
    float4v oacc[2][8] = {};

    // ---- pass 2: e = exp2(exp2(s1+c1) - exp2(s2+c2)); O += P@V
    for (int it = 0; it < NT; ++it) {
        __syncthreads();  // drains tile it's loads
        if (it + 1 < NT) {
            const short* k1b = k1g + (size_t)(it + 1) * 32 * 4096;
            const short* k2b = k2g + (size_t)(it + 1) * 32 * 4096;
            const short* vb = vg + (it + 1) * 32;
            char* dK1 = (char*)(void*)sK1[(it + 1) & 1];
            char* dK2 = (char*)(void*)sK2[(it + 1) & 1];
            char* dV = (char*)(void*)sV[(it + 1) & 1];
#pragma unroll
            for (int i = 0; i < 2; ++i) {
                gl_lds16(k1b + offK[i], dK1 + lbs[i]);
                gl_lds16(k2b + offK[i], dK2 + lbs[i]);
                gl_lds16(vb + offV[i], dV + lbs[i]);
            }
        }
        const short* k1 = sK1[it & 1];
        const short* k2 = sK2[it & 1];
        const short* v = sV[it & 1];
        short* sPw = sP[wid];
#pragma unroll
        for (int kb = 0; kb < 2; ++kb) {
            float4v s1[2] = {}, s2[2] = {};
            int krow = kb * 16 + l15;
            __builtin_amdgcn_s_setprio(1);
#pragma unroll
            for (int ks = 0; ks < 4; ++ks) {
                int q = ks * 4 + quad;
                short8 kf1 = *(const short8*)lds16a(k1, krow, q);
                short8 kf2 = *(const short8*)lds16a(k2, krow, q);
#pragma unroll
                for (int qb = 0; qb < 2; ++qb) {
                    s1[qb] = mfma16(kf1, q1f[qb][ks], s1[qb]);
                    s2[qb] = mfma16(kf2, q2f[qb][ks], s2[qb]);
                }
            }
            __builtin_amdgcn_s_setprio(0);
#pragma unroll
            for (int qb = 0; qb < 2; ++qb) {
                short4v pk;
#pragma unroll
                for (int r = 0; r < 4; ++r) {
                    float u1 = __builtin_amdgcn_exp2f(s1[qb][r] + c1[qb]);
                    float u2 = __builtin_amdgcn_exp2f(s2[qb][r] + c2[qb]);
                    float e = __builtin_amdgcn_exp2f(u1 - u2);
                    lda[qb] += e;
                    pk[r] = f2bf_rhu(e);
                }
                // row = qb*16+l15; keys kb*16+quad*4..+3; 16B chunk p = kb*2+(quad>>1),
                // swizzled p ^ (row&3) = p ^ (l15&3); b64 half = quad&1
                int byte = ((qb << 4) + l15) * 64 +
                           ((((kb << 1) + (quad >> 1)) ^ (l15 & 3)) << 4) +
                           ((quad & 1) << 3);
                *(short4v*)((char*)sPw + byte) = pk;
            }
        }
        // PV: sP wave-private (per-wave DS ordering suffices); sV protected by the
        // top-of-iteration barrier
        __builtin_amdgcn_s_setprio(1);
        {
            short8 pa[2];
#pragma unroll
            for (int qb = 0; qb < 2; ++qb)
                pa[qb] = *(const short8*)((const char*)sPw + ((qb << 4) + l15) * 64 +
                                          ((quad ^ (l15 & 3)) << 4));
#pragma unroll
            for (int nt = 0; nt < 8; ++nt) {
                short8 vbf = *(const short8*)lds4(v, nt * 16 + l15, quad);
#pragma unroll
                for (int qb = 0; qb < 2; ++qb)
                    oacc[qb][nt] = mfma16(pa[qb], vbf, oacc[qb][nt]);
            }
        }
        __builtin_amdgcn_s_setprio(0);
    }
    // lda: reduce across quads (keys), then redistribute to acc layout
#pragma unroll
    for (int qb = 0; qb < 2; ++qb) {
        lda[qb] += __shfl_xor(lda[qb], 16, 64);
        lda[qb] += __shfl_xor(lda[qb], 32, 64);
    }
    float ild[2][4];
#pragma unroll
    for (int qb = 0; qb < 2; ++qb)
#pragma unroll
        for (int r = 0; r < 4; ++r)
            ild[qb][r] = 1.0f / __shfl(lda[qb], (quad << 4) + (quad << 2) + r, 64);
#pragma unroll
    for (int qb = 0; qb < 2; ++qb) {
#pragma unroll
        for (int nt = 0; nt < 8; ++nt)
#pragma unroll
            for (int r = 0; r < 4; ++r) {
                int row = b * S_LEN + wrow + qb * 16 + quad * 4 + r;
                int col = h * DHEAD + nt * 16 + l15;
                AO[(size_t)row * 2048 + col] = oacc[qb][nt][r] * ild[qb][r];
            }
    }
}

// ---------------- RMS norm + scale * (1 - mean(lam)), f32 -> bf16 ----------------
__global__ __launch_bounds__(256)
void rms_kernel(const float* __restrict__ AO, const float* __restrict__ gs,
                const float* __restrict__ lam, short* __restrict__ Y) {
    int row = blockIdx.x, tid = threadIdx.x;
    const float* x = AO + (size_t)row * 2048;
    float4v v0 = *(const float4v*)(x + tid * 8);
    float4v v1 = *(const float4v*)(x + tid * 8 + 4);
    float ss = 0;
#pragma unroll
    for (int j = 0; j < 4; ++j) ss += v0[j] * v0[j] + v1[j] * v1[j];
#pragma unroll
    for (int off = 32; off > 0; off >>= 1) ss += __shfl_xor(ss, off, 64);
    __shared__ float wsum[4];
    if ((tid & 63) == 0) wsum[tid >> 6] = ss;
    __syncthreads();
    float tot = wsum[0] + wsum[1] + wsum[2] + wsum[3];
    float lm = 0;
#pragma unroll
    for (int i = 0; i < 16; ++i) lm += lam[i];
    float f = (1.0f - lm * (1.0f / 16.0f)) * rsqrtf(tot * (1.0f / 2048.0f) + 1e-6f);
    float4v g0 = *(const float4v*)(gs + tid * 8);
    float4v g1 = *(const float4v*)(gs + tid * 8 + 4);
    short4v o0, o1;
#pragma unroll
    for (int j = 0; j < 4; ++j) {
        o0[j] = f2bf(v0[j] * f * g0[j]);
        o1[j] = f2bf(v1[j] * f * g1[j]);
    }
    *(short4v*)(Y + (size_t)row * 2048 + tid * 8) = o0;
    *(short4v*)(Y + (size_t)row * 2048 + tid * 8 + 4) = o1;
}

extern "C" void kernel_launch(void* const* d_in, const int* in_sizes, int n_in,
                              void* d_out, int out_size, void* d_ws, size_t ws_size,
                              hipStream_t stream) {
    const float* x = (const float*)d_in[0];
    const float* Wq = (const float*)d_in[1];
    const float* Wk = (const float*)d_in[2];
    const float* Wv = (const float*)d_in[3];
    const float* Wo = (const float*)d_in[4];
    const float* nsc = (const float*)d_in[5];
    const float* lam = (const float*)d_in[6];
    float* out = (float*)d_out;
    (void)in_sizes; (void)n_in; (void)out_size; (void)ws_size;

    char* ws = (char*)d_ws;
    short* Xb  = (short*)(ws);                 // 16 MiB  [4096][2048]
    short* Wqt = (short*)(ws + 16777216);      // 16 MiB  [4096][2048]
    short* Wkt = (short*)(ws + 33554432);      // 16 MiB  [4096][2048]
    short* Wvt = (short*)(ws + 50331648);      //  8 MiB  [2048][2048]
    short* Wot = (short*)(ws + 58720256);      //  8 MiB  [2048][2048]
    short* Cq  = (short*)(ws + 67108864);      // 32 MiB  [4096][4096]
    short* Ck  = (short*)(ws + 100663296);     // 32 MiB  [4096][4096]
    short* Vt  = (short*)(ws + 134217728);     // 16 MiB  [2][16][128][2048]
    float* AO  = (float*)(ws + 16777216);      // 32 MiB, overlays Wqt+Wkt (dead by then)
    short* Nrm = (short*)(ws);                 // 16 MiB, overlays Xb (dead by then)

    // QKSCALE = (1/sqrt(128)) * log2(e), folded into Wq so scores exit the MFMA
    // in log2-domain
    const float QKSCALE = 0.12752965213246994f;

    cvt_bf16<<<8192, 256, 0, stream>>>(x, Xb);
    tposew<<<dim3(128, 64), 256, 0, stream>>>(Wq, Wqt, 2048, 4096, QKSCALE);
    tposew<<<dim3(128, 64), 256, 0, stream>>>(Wk, Wkt, 2048, 4096, 1.0f);
    tposew<<<dim3(64, 64), 256, 0, stream>>>(Wv, Wvt, 2048, 2048, 1.0f);
    tposew<<<dim3(64, 64), 256, 0, stream>>>(Wo, Wot, 2048, 2048, 1.0f);

    gemm_bt<0><<<dim3(32, 32), 256, 0, stream>>>(Xb, Wqt, (void*)Cq, 4096, 4096, 2048);
    gemm_bt<0><<<dim3(32, 32), 256, 0, stream>>>(Xb, Wkt, (void*)Ck, 4096, 4096, 2048);
    gemm_bt<2><<<dim3(16, 32), 256, 0, stream>>>(Xb, Wvt, (void*)Vt, 4096, 2048, 2048);

    attn_kernel<<<dim3(512), 256, 0, stream>>>(Cq, Ck, Vt, lam, AO);
    rms_kernel<<<4096, 256, 0, stream>>>(AO, nsc, lam, Nrm);
    gemm_bt<1><<<dim3(16, 32), 256, 0, stream>>>(Nrm, Wot, (void*)out, 4096, 2048, 2048);
}